// Round 3
// baseline (339.553 us; speedup 1.0000x reference)
//
#include <hip/hip_runtime.h>
#include <hip/hip_bf16.h>

// ---------------------------------------------------------------------------
// CDAE forward. Round 3: ratings kernel is L2-miss bound on the de_emb gather
// (R2: FETCH_SIZE=144MB vs ~12MB ideal; 28% HBM, 31% VALU). Fix: counting-sort
// pairs by item bucket (item>>9, ~100KB de_emb per bucket) so the resident
// working set of de_emb is a few hundred KB -> L2-hit on every XCD.
// Also fuse k_mask into the histogram pass and k_reg_user into k_reg_items.
// ---------------------------------------------------------------------------
#define PARTITIONABLE 1

__device__ __forceinline__ unsigned rotl32(unsigned x, int r) {
    return (x << r) | (x >> (32 - r));
}

__device__ __forceinline__ void threefry2x32(unsigned k0, unsigned k1,
                                             unsigned& x0, unsigned& x1) {
    unsigned ks0 = k0, ks1 = k1, ks2 = k0 ^ k1 ^ 0x1BD11BDAu;
    x0 += ks0; x1 += ks1;
#define TF_R(r) { x0 += x1; x1 = rotl32(x1, r); x1 ^= x0; }
    TF_R(13) TF_R(15) TF_R(26) TF_R(6)   x0 += ks1; x1 += ks2 + 1u;
    TF_R(17) TF_R(29) TF_R(16) TF_R(24)  x0 += ks2; x1 += ks0 + 2u;
    TF_R(13) TF_R(15) TF_R(26) TF_R(6)   x0 += ks0; x1 += ks1 + 3u;
    TF_R(17) TF_R(29) TF_R(16) TF_R(24)  x0 += ks1; x1 += ks2 + 4u;
    TF_R(13) TF_R(15) TF_R(26) TF_R(6)   x0 += ks2; x1 += ks0 + 5u;
#undef TF_R
}

__device__ __forceinline__ bool keep_mask(int i, int nnz) {
#if PARTITIONABLE
    unsigned x0 = 0u, x1 = (unsigned)i;
    threefry2x32(0u, 42u, x0, x1);
    unsigned bits = x0 ^ x1;
#else
    int half = nnz >> 1;
    int j = (i < half) ? i : i - half;
    unsigned x0 = (unsigned)j, x1 = (unsigned)(j + half);
    threefry2x32(0u, 42u, x0, x1);
    unsigned bits = (i < half) ? x0 : x1;
#endif
    float u = __uint_as_float((bits >> 9) | 0x3f800000u) - 1.0f;
    return u < 0.8f;
}

// ===================== counting sort of pairs by item bucket ================
// NB=256 bucket slots, bucket = item>>9 (<196 for NUM_ITEMS=1e5).
// Grid A/C: 256 blocks x 256 threads, each block owns N/256 contiguous pairs.

// --- A: per-block histogram, fused with item-mask set ----------------------
__global__ void k_hist(const int* __restrict__ bat_items, unsigned char* __restrict__ mask,
                       int* __restrict__ blkcnt, int N) {
    __shared__ int h[256];
    h[threadIdx.x] = 0;
    __syncthreads();
    const int per = N / gridDim.x;
    const int base = blockIdx.x * per;
    for (int it = 0; it < per; it += 256) {
        int item = bat_items[base + it + threadIdx.x];
        mask[item] = 1;
        atomicAdd(&h[item >> 9], 1);
    }
    __syncthreads();
    blkcnt[blockIdx.x * 256 + threadIdx.x] = h[threadIdx.x];
}

// --- B: single block: per-bucket running offsets + bucket bases ------------
__global__ void k_scan(int* __restrict__ blkcnt, int* __restrict__ bucket_base, int nblk) {
    const int bkt = threadIdx.x;           // 256 threads = 256 buckets
    int run = 0;
    for (int blk = 0; blk < nblk; ++blk) {
        int v = blkcnt[blk * 256 + bkt];
        blkcnt[blk * 256 + bkt] = run;     // exclusive within-bucket offset
        run += v;
    }
    __shared__ int tot[256];
    tot[bkt] = run;
    __syncthreads();
    int mine = run;
    for (int d = 1; d < 256; d <<= 1) {    // Hillis-Steele inclusive scan
        int v = (bkt >= d) ? tot[bkt - d] : 0;
        __syncthreads();
        tot[bkt] += v;
        __syncthreads();
    }
    bucket_base[bkt] = tot[bkt] - mine;    // exclusive bucket base
}

// --- C: scatter packed payload (item<<32 | bidx<<20 | n) into perm ---------
__global__ void k_permute(const int* __restrict__ bat_idx, const int* __restrict__ bat_items,
                          const int* __restrict__ blkcnt, const int* __restrict__ bucket_base,
                          unsigned long long* __restrict__ perm, int N) {
    __shared__ int cur[256];
    cur[threadIdx.x] = blkcnt[blockIdx.x * 256 + threadIdx.x] + bucket_base[threadIdx.x];
    __syncthreads();
    const int per = N / gridDim.x;
    const int base = blockIdx.x * per;
    for (int it = 0; it < per; it += 256) {
        int n = base + it + threadIdx.x;
        int item = bat_items[n];
        int bidx = bat_idx[n];
        int pos = atomicAdd(&cur[item >> 9], 1);
        perm[pos] = ((unsigned long long)(unsigned)item << 32)
                  | ((unsigned)bidx << 20) | (unsigned)n;
    }
}

// --- D: ratings over permuted (bucket-ordered) pairs -----------------------
__global__ void k_ratings_perm(const float* __restrict__ hidden, const float* __restrict__ de_emb,
                               const float* __restrict__ de_bias,
                               const unsigned long long* __restrict__ perm,
                               float* __restrict__ out, int N) {
    int t = blockIdx.x * blockDim.x + threadIdx.x;
    int j = t >> 4, l = t & 15;
    if (j >= N) return;
    unsigned long long p = perm[j];
    int n    = (int)(p & 0xFFFFFu);
    int bidx = (int)((p >> 20) & 0xFFFu);
    int item = (int)(p >> 32);
    float4 hv = *reinterpret_cast<const float4*>(hidden + (size_t)bidx * 64 + l * 4);
    float4 dv = *reinterpret_cast<const float4*>(de_emb + (size_t)item * 64 + l * 4);
    float s = hv.x * dv.x + hv.y * dv.y + hv.z * dv.z + hv.w * dv.w;
    s += __shfl_xor(s, 1);
    s += __shfl_xor(s, 2);
    s += __shfl_xor(s, 4);
    s += __shfl_xor(s, 8);
    if (l == 0) out[n] = s + de_bias[item];
}

// ===================== fallback (R2) path ===================================
__global__ void k_mask(const int* __restrict__ bat_items, unsigned char* __restrict__ mask,
                       int N) {
    int t = blockIdx.x * blockDim.x + threadIdx.x;
    if (t < N) mask[bat_items[t]] = 1;
}

__global__ void k_ratings(const float* __restrict__ hidden, const float* __restrict__ de_emb,
                          const float* __restrict__ de_bias,
                          const int* __restrict__ bat_idx, const int* __restrict__ bat_items,
                          float* __restrict__ out, int N) {
    int t = blockIdx.x * blockDim.x + threadIdx.x;
    int n = t >> 4, l = t & 15;
    if (n >= N) return;
    int b  = bat_idx[n];
    int it = bat_items[n];
    float4 hv = *reinterpret_cast<const float4*>(hidden + (size_t)b  * 64 + l * 4);
    float4 dv = *reinterpret_cast<const float4*>(de_emb + (size_t)it * 64 + l * 4);
    float s = hv.x * dv.x + hv.y * dv.y + hv.z * dv.z + hv.w * dv.w;
    s += __shfl_xor(s, 1);
    s += __shfl_xor(s, 2);
    s += __shfl_xor(s, 4);
    s += __shfl_xor(s, 8);
    if (l == 0) out[n] = s + de_bias[it];
}

// ===================== hidden construction ==================================
__global__ void k_scatter(const int* __restrict__ sp_row, const int* __restrict__ sp_col,
                          const float* __restrict__ en_emb, float* __restrict__ hidden,
                          int nnz) {
    int t = blockIdx.x * blockDim.x + threadIdx.x;
    int i = t >> 6;
    int lane = t & 63;
    if (i >= nnz) return;
    if (!keep_mask(i, nnz)) return;
    int row = sp_row[i];
    int col = sp_col[i];
    float v = 1.25f * en_emb[(size_t)col * 64 + lane];
    atomicAdd(&hidden[row * 64 + lane], v);
}

__global__ void k_hfinish(float* __restrict__ hidden, const float* __restrict__ user_emb,
                          const int* __restrict__ user_ids, const float* __restrict__ en_off,
                          int B) {
    int t = blockIdx.x * blockDim.x + threadIdx.x;
    if (t >= B * 64) return;
    int b = t >> 6, d = t & 63;
    int uid = user_ids[b];
    float h = hidden[t] + user_emb[(size_t)uid * 64 + d] + en_off[d];
    hidden[t] = tanhf(h);
}

// ===================== fused regularization =================================
__global__ void k_reg(const unsigned char* __restrict__ mask,
                      const float* __restrict__ en_emb, const float* __restrict__ de_emb,
                      const float* __restrict__ de_bias,
                      const float* __restrict__ user_emb, const int* __restrict__ user_ids,
                      const float* __restrict__ en_off,
                      float* __restrict__ reg, int num_items, int B) {
    const int stride = gridDim.x * blockDim.x;
    float s = 0.f;
    // masked item part
    for (int t = blockIdx.x * blockDim.x + threadIdx.x; t < num_items * 16; t += stride) {
        int i = t >> 4, l = t & 15;
        if (mask[i]) {
            float4 e = *reinterpret_cast<const float4*>(en_emb + (size_t)i * 64 + l * 4);
            float4 d = *reinterpret_cast<const float4*>(de_emb + (size_t)i * 64 + l * 4);
            s += e.x*e.x + e.y*e.y + e.z*e.z + e.w*e.w
               + d.x*d.x + d.y*d.y + d.z*d.z + d.w*d.w;
            if (l == 0) { float bb = de_bias[i]; s += bb * bb; }
        }
    }
    // user part (dups included)
    for (int t = blockIdx.x * blockDim.x + threadIdx.x; t < B * 16; t += stride) {
        int b = t >> 4, l = t & 15;
        int uid = user_ids[b];
        float4 u = *reinterpret_cast<const float4*>(user_emb + (size_t)uid * 64 + l * 4);
        s += u.x*u.x + u.y*u.y + u.z*u.z + u.w*u.w;
    }
    if (blockIdx.x == 0 && threadIdx.x < 64) {
        float o = en_off[threadIdx.x];
        s += o * o;
    }
    for (int m = 1; m < 64; m <<= 1) s += __shfl_xor(s, m);
    __shared__ float wsum[4];
    if ((threadIdx.x & 63) == 0) wsum[threadIdx.x >> 6] = s;
    __syncthreads();
    if (threadIdx.x == 0)
        atomicAdd(reg, 0.5f * (wsum[0] + wsum[1] + wsum[2] + wsum[3]));
}

extern "C" void kernel_launch(void* const* d_in, const int* in_sizes, int n_in,
                              void* d_out, int out_size, void* d_ws, size_t ws_size,
                              hipStream_t stream) {
    const int*   user_ids  = (const int*)  d_in[0];
    const int*   bat_idx   = (const int*)  d_in[1];
    const int*   sp_row    = (const int*)  d_in[2];
    const int*   sp_col    = (const int*)  d_in[3];
    const int*   bat_items = (const int*)  d_in[4];
    const float* en_emb    = (const float*)d_in[5];
    const float* en_off    = (const float*)d_in[6];
    const float* de_emb    = (const float*)d_in[7];
    const float* de_bias   = (const float*)d_in[8];
    const float* user_emb  = (const float*)d_in[9];

    const int B         = in_sizes[0];
    const int N         = in_sizes[1];
    const int NNZ       = in_sizes[2];
    const int NUM_ITEMS = in_sizes[8];

    float* out = (float*)d_out;        // ratings [N]
    float* reg = out + N;              // reg_loss scalar

    // workspace layout
    char* ws = (char*)d_ws;
    float*         hidden      = (float*)ws;                      // B*64*4 = 1 MiB
    size_t         off         = (size_t)B * 64 * sizeof(float);
    unsigned char* mask        = (unsigned char*)(ws + off);      // NUM_ITEMS bytes
    off += ((size_t)NUM_ITEMS + 255) & ~(size_t)255;
    int*           blkcnt      = (int*)(ws + off);                // 256*256*4
    off += 256 * 256 * sizeof(int);
    int*           bucket_base = (int*)(ws + off);                // 256*4
    off += 256 * sizeof(int);
    off = (off + 7) & ~(size_t)7;
    unsigned long long* perm   = (unsigned long long*)(ws + off); // N*8
    off += (size_t)N * 8;

    const bool sorted_path =
        (ws_size >= off) && (N == (1 << 20)) && (B <= 4096) && (NUM_ITEMS <= (1 << 17));

    hipMemsetAsync(hidden, 0, (size_t)B * 64 * sizeof(float), stream);
    hipMemsetAsync(mask, 0, (size_t)NUM_ITEMS, stream);
    hipMemsetAsync(reg, 0, sizeof(float), stream);

    if (sorted_path) {
        k_hist   <<<256, 256, 0, stream>>>(bat_items, mask, blkcnt, N);
        k_scan   <<<1, 256, 0, stream>>>(blkcnt, bucket_base, 256);
        k_permute<<<256, 256, 0, stream>>>(bat_idx, bat_items, blkcnt, bucket_base, perm, N);
    } else {
        k_mask<<<(N + 255) / 256, 256, 0, stream>>>(bat_items, mask, N);
    }

    k_scatter<<<(NNZ * 64 + 255) / 256, 256, 0, stream>>>(sp_row, sp_col, en_emb, hidden, NNZ);
    k_hfinish<<<(B * 64 + 255) / 256, 256, 0, stream>>>(hidden, user_emb, user_ids, en_off, B);

    if (sorted_path) {
        k_ratings_perm<<<(int)(((size_t)N * 16 + 255) / 256), 256, 0, stream>>>(
            hidden, de_emb, de_bias, perm, out, N);
    } else {
        k_ratings<<<(int)(((size_t)N * 16 + 255) / 256), 256, 0, stream>>>(
            hidden, de_emb, de_bias, bat_idx, bat_items, out, N);
    }

    k_reg<<<256, 256, 0, stream>>>(mask, en_emb, de_emb, de_bias,
                                   user_emb, user_ids, en_off, reg, NUM_ITEMS, B);
}

// Round 4
// 263.861 us; speedup vs baseline: 1.2869x; 1.2869x over previous
//
#include <hip/hip_runtime.h>
#include <hip/hip_bf16.h>

// ---------------------------------------------------------------------------
// CDAE forward. Round 4.
// R3 post-mortem: (a) per-XCD L2s each refetched the active de_emb slice
// (FETCH only 144->88MB, floor for all-XCD-replication is 8x25.6=205MB);
// (b) scattered 4B out[n] stores -> 9x write amp (WRITE 4->36MB) + RMW fills;
// (c) k_permute scattered 8B writes + serial k_scan cost ~70us.
// Fixes: 8 item-slice buckets pinned to XCDs via blockIdx&7 (round-robin
// dispatch heuristic); all stores coalesced (r_perm[j] then gather-unpermute
// via inv[] which is written coalesced); single-kernel bucketing, registers
// hold payload between phases, contiguous per-(block,bucket) runs.
// ---------------------------------------------------------------------------
#define PARTITIONABLE 1
#define NB 8               // buckets == XCDs
#define CAPB 136192        // per-bucket capacity (mult of 16); E[count]=131072, +14 sigma

__device__ __forceinline__ unsigned rotl32(unsigned x, int r) {
    return (x << r) | (x >> (32 - r));
}

__device__ __forceinline__ void threefry2x32(unsigned k0, unsigned k1,
                                             unsigned& x0, unsigned& x1) {
    unsigned ks0 = k0, ks1 = k1, ks2 = k0 ^ k1 ^ 0x1BD11BDAu;
    x0 += ks0; x1 += ks1;
#define TF_R(r) { x0 += x1; x1 = rotl32(x1, r); x1 ^= x0; }
    TF_R(13) TF_R(15) TF_R(26) TF_R(6)   x0 += ks1; x1 += ks2 + 1u;
    TF_R(17) TF_R(29) TF_R(16) TF_R(24)  x0 += ks2; x1 += ks0 + 2u;
    TF_R(13) TF_R(15) TF_R(26) TF_R(6)   x0 += ks0; x1 += ks1 + 3u;
    TF_R(17) TF_R(29) TF_R(16) TF_R(24)  x0 += ks1; x1 += ks2 + 4u;
    TF_R(13) TF_R(15) TF_R(26) TF_R(6)   x0 += ks2; x1 += ks0 + 5u;
#undef TF_R
}

__device__ __forceinline__ bool keep_mask(int i, int nnz) {
#if PARTITIONABLE
    unsigned x0 = 0u, x1 = (unsigned)i;
    threefry2x32(0u, 42u, x0, x1);
    unsigned bits = x0 ^ x1;
#else
    int half = nnz >> 1;
    int j = (i < half) ? i : i - half;
    unsigned x0 = (unsigned)j, x1 = (unsigned)(j + half);
    threefry2x32(0u, 42u, x0, x1);
    unsigned bits = (i < half) ? x0 : x1;
#endif
    float u = __uint_as_float((bits >> 9) | 0x3f800000u) - 1.0f;
    return u < 0.8f;
}

// ===================== bucketing (one kernel, no scan) ======================
// 256 blocks x 256 threads; each block owns N/256=4096 consecutive pairs,
// 16 per thread, payload cached in registers between phases.
__global__ void k_bucket(const int* __restrict__ bat_idx, const int* __restrict__ bat_items,
                         unsigned char* __restrict__ mask, int* __restrict__ cursor,
                         unsigned* __restrict__ perm, unsigned* __restrict__ inv,
                         int N, int num_items) {
    __shared__ int h[NB];
    if (threadIdx.x < NB) h[threadIdx.x] = 0;
    __syncthreads();
    const int per = N / gridDim.x;                 // 4096
    const int base_n = blockIdx.x * per;
    const int iters = per / blockDim.x;            // 16
    unsigned packed[16];
    int bkt[16];
    for (int it = 0; it < iters; ++it) {
        int n = base_n + it * blockDim.x + threadIdx.x;
        int item = bat_items[n];
        int bidx = bat_idx[n];
        mask[item] = 1;
        int b = (int)(((unsigned long long)(unsigned)item * NB) / (unsigned)num_items);
        packed[it] = ((unsigned)item << 12) | (unsigned)bidx;   // item:17 | bidx:12
        bkt[it] = b;
        atomicAdd(&h[b], 1);
    }
    __syncthreads();
    if (threadIdx.x < NB) {
        int cnt = h[threadIdx.x];
        h[threadIdx.x] = atomicAdd(&cursor[threadIdx.x], cnt);  // h becomes running cursor
    }
    __syncthreads();
    for (int it = 0; it < iters; ++it) {
        int n = base_n + it * blockDim.x + threadIdx.x;
        int b = bkt[it];
        int pos = atomicAdd(&h[b], 1);
        unsigned gpos = (unsigned)b * CAPB + (unsigned)min(pos, CAPB - 1);
        perm[gpos] = packed[it];   // contiguous per-(block,bucket) runs (~2KB)
        inv[n] = gpos;             // coalesced
    }
}

// ===================== ratings over XCD-pinned buckets ======================
// grid = NB * (CAPB/16); bkt = blockIdx&7 -> XCD via round-robin dispatch.
__global__ void k_ratings_bkt(const float* __restrict__ hidden, const float* __restrict__ de_emb,
                              const float* __restrict__ de_bias,
                              const unsigned* __restrict__ perm, const int* __restrict__ cursor,
                              float* __restrict__ r_perm) {
    int bkt = blockIdx.x & (NB - 1);
    int idx = blockIdx.x >> 3;
    int g = threadIdx.x >> 4, l = threadIdx.x & 15;
    int slot = idx * 16 + g;
    if (slot >= cursor[bkt]) return;
    int j = bkt * CAPB + slot;
    unsigned p = perm[j];
    int item = (int)(p >> 12);
    int bidx = (int)(p & 0xFFFu);
    float4 hv = *reinterpret_cast<const float4*>(hidden + (size_t)bidx * 64 + l * 4);
    float4 dv = *reinterpret_cast<const float4*>(de_emb + (size_t)item * 64 + l * 4);
    float s = hv.x * dv.x + hv.y * dv.y + hv.z * dv.z + hv.w * dv.w;
    s += __shfl_xor(s, 1);
    s += __shfl_xor(s, 2);
    s += __shfl_xor(s, 4);
    s += __shfl_xor(s, 8);
    if (l == 0) r_perm[j] = s + de_bias[item];     // coalesced (64B per block-group)
}

// ===================== unpermute: gather, all stores coalesced ==============
__global__ void k_unperm(const unsigned* __restrict__ inv, const float* __restrict__ r_perm,
                         float* __restrict__ out, int N) {
    int t = blockIdx.x * blockDim.x + threadIdx.x;
    if (t < N) out[t] = r_perm[inv[t]];
}

// ===================== fallback (R2) path ===================================
__global__ void k_mask(const int* __restrict__ bat_items, unsigned char* __restrict__ mask,
                       int N) {
    int t = blockIdx.x * blockDim.x + threadIdx.x;
    if (t < N) mask[bat_items[t]] = 1;
}

__global__ void k_ratings(const float* __restrict__ hidden, const float* __restrict__ de_emb,
                          const float* __restrict__ de_bias,
                          const int* __restrict__ bat_idx, const int* __restrict__ bat_items,
                          float* __restrict__ out, int N) {
    int t = blockIdx.x * blockDim.x + threadIdx.x;
    int n = t >> 4, l = t & 15;
    if (n >= N) return;
    int b  = bat_idx[n];
    int it = bat_items[n];
    float4 hv = *reinterpret_cast<const float4*>(hidden + (size_t)b  * 64 + l * 4);
    float4 dv = *reinterpret_cast<const float4*>(de_emb + (size_t)it * 64 + l * 4);
    float s = hv.x * dv.x + hv.y * dv.y + hv.z * dv.z + hv.w * dv.w;
    s += __shfl_xor(s, 1);
    s += __shfl_xor(s, 2);
    s += __shfl_xor(s, 4);
    s += __shfl_xor(s, 8);
    if (l == 0) out[n] = s + de_bias[it];
}

// ===================== hidden construction ==================================
__global__ void k_scatter(const int* __restrict__ sp_row, const int* __restrict__ sp_col,
                          const float* __restrict__ en_emb, float* __restrict__ hidden,
                          int nnz) {
    int t = blockIdx.x * blockDim.x + threadIdx.x;
    int i = t >> 6;
    int lane = t & 63;
    if (i >= nnz) return;
    if (!keep_mask(i, nnz)) return;
    int row = sp_row[i];
    int col = sp_col[i];
    float v = 1.25f * en_emb[(size_t)col * 64 + lane];
    atomicAdd(&hidden[row * 64 + lane], v);
}

__global__ void k_hfinish(float* __restrict__ hidden, const float* __restrict__ user_emb,
                          const int* __restrict__ user_ids, const float* __restrict__ en_off,
                          int B) {
    int t = blockIdx.x * blockDim.x + threadIdx.x;
    if (t >= B * 64) return;
    int b = t >> 6, d = t & 63;
    int uid = user_ids[b];
    float h = hidden[t] + user_emb[(size_t)uid * 64 + d] + en_off[d];
    hidden[t] = tanhf(h);
}

// ===================== fused regularization =================================
__global__ void k_reg(const unsigned char* __restrict__ mask,
                      const float* __restrict__ en_emb, const float* __restrict__ de_emb,
                      const float* __restrict__ de_bias,
                      const float* __restrict__ user_emb, const int* __restrict__ user_ids,
                      const float* __restrict__ en_off,
                      float* __restrict__ reg, int num_items, int B) {
    const int stride = gridDim.x * blockDim.x;
    float s = 0.f;
    for (int t = blockIdx.x * blockDim.x + threadIdx.x; t < num_items * 16; t += stride) {
        int i = t >> 4, l = t & 15;
        if (mask[i]) {
            float4 e = *reinterpret_cast<const float4*>(en_emb + (size_t)i * 64 + l * 4);
            float4 d = *reinterpret_cast<const float4*>(de_emb + (size_t)i * 64 + l * 4);
            s += e.x*e.x + e.y*e.y + e.z*e.z + e.w*e.w
               + d.x*d.x + d.y*d.y + d.z*d.z + d.w*d.w;
            if (l == 0) { float bb = de_bias[i]; s += bb * bb; }
        }
    }
    for (int t = blockIdx.x * blockDim.x + threadIdx.x; t < B * 16; t += stride) {
        int b = t >> 4, l = t & 15;
        int uid = user_ids[b];
        float4 u = *reinterpret_cast<const float4*>(user_emb + (size_t)uid * 64 + l * 4);
        s += u.x*u.x + u.y*u.y + u.z*u.z + u.w*u.w;
    }
    if (blockIdx.x == 0 && threadIdx.x < 64) {
        float o = en_off[threadIdx.x];
        s += o * o;
    }
    for (int m = 1; m < 64; m <<= 1) s += __shfl_xor(s, m);
    __shared__ float wsum[4];
    if ((threadIdx.x & 63) == 0) wsum[threadIdx.x >> 6] = s;
    __syncthreads();
    if (threadIdx.x == 0)
        atomicAdd(reg, 0.5f * (wsum[0] + wsum[1] + wsum[2] + wsum[3]));
}

extern "C" void kernel_launch(void* const* d_in, const int* in_sizes, int n_in,
                              void* d_out, int out_size, void* d_ws, size_t ws_size,
                              hipStream_t stream) {
    const int*   user_ids  = (const int*)  d_in[0];
    const int*   bat_idx   = (const int*)  d_in[1];
    const int*   sp_row    = (const int*)  d_in[2];
    const int*   sp_col    = (const int*)  d_in[3];
    const int*   bat_items = (const int*)  d_in[4];
    const float* en_emb    = (const float*)d_in[5];
    const float* en_off    = (const float*)d_in[6];
    const float* de_emb    = (const float*)d_in[7];
    const float* de_bias   = (const float*)d_in[8];
    const float* user_emb  = (const float*)d_in[9];

    const int B         = in_sizes[0];
    const int N         = in_sizes[1];
    const int NNZ       = in_sizes[2];
    const int NUM_ITEMS = in_sizes[8];

    float* out = (float*)d_out;        // ratings [N]
    float* reg = out + N;              // reg_loss scalar

    // workspace layout
    char* ws = (char*)d_ws;
    size_t off = 0;
    float* hidden = (float*)(ws + off);           off += (size_t)B * 64 * sizeof(float);
    unsigned char* mask = (unsigned char*)(ws + off);
    off += ((size_t)NUM_ITEMS + 255) & ~(size_t)255;
    int* cursor = (int*)(ws + off);               off += 256;
    unsigned* perm   = (unsigned*)(ws + off);     off += (size_t)NB * CAPB * 4;
    unsigned* inv    = (unsigned*)(ws + off);     off += (size_t)N * 4;
    float*    r_perm = (float*)(ws + off);        off += (size_t)NB * CAPB * 4;

    const bool sorted_path =
        (ws_size >= off) && (N == (1 << 20)) && (B <= 4096) &&
        (NUM_ITEMS <= (1 << 17)) && (NUM_ITEMS >= 65536);

    hipMemsetAsync(hidden, 0, (size_t)B * 64 * sizeof(float), stream);
    hipMemsetAsync(mask, 0, (size_t)NUM_ITEMS, stream);
    hipMemsetAsync(reg, 0, sizeof(float), stream);

    if (sorted_path) {
        hipMemsetAsync(cursor, 0, NB * sizeof(int), stream);
        k_bucket<<<256, 256, 0, stream>>>(bat_idx, bat_items, mask, cursor, perm, inv,
                                          N, NUM_ITEMS);
    } else {
        k_mask<<<(N + 255) / 256, 256, 0, stream>>>(bat_items, mask, N);
    }

    k_scatter<<<(NNZ * 64 + 255) / 256, 256, 0, stream>>>(sp_row, sp_col, en_emb, hidden, NNZ);
    k_hfinish<<<(B * 64 + 255) / 256, 256, 0, stream>>>(hidden, user_emb, user_ids, en_off, B);

    if (sorted_path) {
        k_ratings_bkt<<<NB * (CAPB / 16), 256, 0, stream>>>(
            hidden, de_emb, de_bias, perm, cursor, r_perm);
        k_unperm<<<(N + 255) / 256, 256, 0, stream>>>(inv, r_perm, out, N);
    } else {
        k_ratings<<<(int)(((size_t)N * 16 + 255) / 256), 256, 0, stream>>>(
            hidden, de_emb, de_bias, bat_idx, bat_items, out, N);
    }

    k_reg<<<256, 256, 0, stream>>>(mask, en_emb, de_emb, de_bias,
                                   user_emb, user_ids, en_off, reg, NUM_ITEMS, B);
}

// Round 5
// 245.027 us; speedup vs baseline: 1.3858x; 1.0769x over previous
//
#include <hip/hip_runtime.h>
#include <hip/hip_bf16.h>

// ---------------------------------------------------------------------------
// CDAE forward. Round 5: fat grid-stride everywhere.
// R4 post-mortem: ratings FETCH fixed (88.6->28.9MB) but dur 74->57us with
// HBM 7%, VALU 36%, LDS 0 -> nothing visibly busy. 68096 blocks / 57.2us =
// 0.84ns/block ~= 2cyc/block == device workgroup-dispatch rate. Same signature
// fits R2 ratings (65536 blk/66us) and the unaccounted k_scatter (51200 blk).
// Fix: 2048-block grid-stride kernels, 16-lane groups loop ~32 pairs each,
// 2-way unroll for independent gather chains. Keep R4 bucket locality
// (FETCH 5x win) + coalesced-store structure. Merge memsets.
// ---------------------------------------------------------------------------
#define PARTITIONABLE 1
#define NB 8               // item-slice buckets == XCDs (blockIdx&7 pinning)
#define CAPB 136192        // per-bucket capacity; E=131072, +14 sigma
#define FATB 2048          // fat grid size

__device__ __forceinline__ unsigned rotl32(unsigned x, int r) {
    return (x << r) | (x >> (32 - r));
}

__device__ __forceinline__ void threefry2x32(unsigned k0, unsigned k1,
                                             unsigned& x0, unsigned& x1) {
    unsigned ks0 = k0, ks1 = k1, ks2 = k0 ^ k1 ^ 0x1BD11BDAu;
    x0 += ks0; x1 += ks1;
#define TF_R(r) { x0 += x1; x1 = rotl32(x1, r); x1 ^= x0; }
    TF_R(13) TF_R(15) TF_R(26) TF_R(6)   x0 += ks1; x1 += ks2 + 1u;
    TF_R(17) TF_R(29) TF_R(16) TF_R(24)  x0 += ks2; x1 += ks0 + 2u;
    TF_R(13) TF_R(15) TF_R(26) TF_R(6)   x0 += ks0; x1 += ks1 + 3u;
    TF_R(17) TF_R(29) TF_R(16) TF_R(24)  x0 += ks1; x1 += ks2 + 4u;
    TF_R(13) TF_R(15) TF_R(26) TF_R(6)   x0 += ks2; x1 += ks0 + 5u;
#undef TF_R
}

__device__ __forceinline__ bool keep_mask(int i, int nnz) {
#if PARTITIONABLE
    unsigned x0 = 0u, x1 = (unsigned)i;
    threefry2x32(0u, 42u, x0, x1);
    unsigned bits = x0 ^ x1;
#else
    int half = nnz >> 1;
    int j = (i < half) ? i : i - half;
    unsigned x0 = (unsigned)j, x1 = (unsigned)(j + half);
    threefry2x32(0u, 42u, x0, x1);
    unsigned bits = (i < half) ? x0 : x1;
#endif
    float u = __uint_as_float((bits >> 9) | 0x3f800000u) - 1.0f;
    return u < 0.8f;
}

// ===================== bucketing (one kernel, no scan) ======================
__global__ void k_bucket(const int* __restrict__ bat_idx, const int* __restrict__ bat_items,
                         unsigned char* __restrict__ mask, int* __restrict__ cursor,
                         unsigned* __restrict__ perm, unsigned* __restrict__ inv,
                         int N, int num_items) {
    __shared__ int h[NB];
    if (threadIdx.x < NB) h[threadIdx.x] = 0;
    __syncthreads();
    const int per = N / gridDim.x;                 // 4096
    const int base_n = blockIdx.x * per;
    const int iters = per / blockDim.x;            // 16
    unsigned packed[16];
    int bkt[16];
    for (int it = 0; it < iters; ++it) {
        int n = base_n + it * blockDim.x + threadIdx.x;
        int item = bat_items[n];
        int bidx = bat_idx[n];
        mask[item] = 1;
        int b = (int)(((unsigned long long)(unsigned)item * NB) / (unsigned)num_items);
        packed[it] = ((unsigned)item << 12) | (unsigned)bidx;   // item:17 | bidx:12
        bkt[it] = b;
        atomicAdd(&h[b], 1);
    }
    __syncthreads();
    if (threadIdx.x < NB) {
        int cnt = h[threadIdx.x];
        h[threadIdx.x] = atomicAdd(&cursor[threadIdx.x], cnt);  // h -> running cursor
    }
    __syncthreads();
    for (int it = 0; it < iters; ++it) {
        int n = base_n + it * blockDim.x + threadIdx.x;
        int b = bkt[it];
        int pos = atomicAdd(&h[b], 1);
        unsigned gpos = (unsigned)b * CAPB + (unsigned)min(pos, CAPB - 1);
        perm[gpos] = packed[it];   // contiguous per-(block,bucket) runs
        inv[n] = gpos;             // coalesced
    }
}

// ===================== ratings: fat grid-stride over XCD-pinned buckets =====
__global__ void k_ratings_bkt(const float* __restrict__ hidden, const float* __restrict__ de_emb,
                              const float* __restrict__ de_bias,
                              const unsigned* __restrict__ perm, const int* __restrict__ cursor,
                              float* __restrict__ r_perm) {
    const int bkt = blockIdx.x & (NB - 1);
    const int cnt = cursor[bkt];
    const int l = threadIdx.x & 15;
    const int gid = (blockIdx.x >> 3) * (blockDim.x >> 4) + (threadIdx.x >> 4);
    const int gpb = (gridDim.x >> 3) * (blockDim.x >> 4);   // groups per bucket
    const unsigned* pb = perm + (size_t)bkt * CAPB;
    float* rb = r_perm + (size_t)bkt * CAPB;

    int slot = gid;
    for (; slot + gpb < cnt; slot += 2 * gpb) {             // 2 independent chains
        unsigned p0 = pb[slot];
        unsigned p1 = pb[slot + gpb];
        int it0 = (int)(p0 >> 12), b0 = (int)(p0 & 0xFFFu);
        int it1 = (int)(p1 >> 12), b1 = (int)(p1 & 0xFFFu);
        float4 h0 = *reinterpret_cast<const float4*>(hidden + (size_t)b0 * 64 + l * 4);
        float4 d0 = *reinterpret_cast<const float4*>(de_emb + (size_t)it0 * 64 + l * 4);
        float4 h1 = *reinterpret_cast<const float4*>(hidden + (size_t)b1 * 64 + l * 4);
        float4 d1 = *reinterpret_cast<const float4*>(de_emb + (size_t)it1 * 64 + l * 4);
        float s0 = h0.x*d0.x + h0.y*d0.y + h0.z*d0.z + h0.w*d0.w;
        float s1 = h1.x*d1.x + h1.y*d1.y + h1.z*d1.z + h1.w*d1.w;
        s0 += __shfl_xor(s0, 1); s1 += __shfl_xor(s1, 1);
        s0 += __shfl_xor(s0, 2); s1 += __shfl_xor(s1, 2);
        s0 += __shfl_xor(s0, 4); s1 += __shfl_xor(s1, 4);
        s0 += __shfl_xor(s0, 8); s1 += __shfl_xor(s1, 8);
        if (l == 0) {
            rb[slot]       = s0 + de_bias[it0];
            rb[slot + gpb] = s1 + de_bias[it1];
        }
    }
    for (; slot < cnt; slot += gpb) {
        unsigned p = pb[slot];
        int item = (int)(p >> 12), bidx = (int)(p & 0xFFFu);
        float4 hv = *reinterpret_cast<const float4*>(hidden + (size_t)bidx * 64 + l * 4);
        float4 dv = *reinterpret_cast<const float4*>(de_emb + (size_t)item * 64 + l * 4);
        float s = hv.x*dv.x + hv.y*dv.y + hv.z*dv.z + hv.w*dv.w;
        s += __shfl_xor(s, 1);
        s += __shfl_xor(s, 2);
        s += __shfl_xor(s, 4);
        s += __shfl_xor(s, 8);
        if (l == 0) rb[slot] = s + de_bias[item];
    }
}

// ===================== unpermute: gather, coalesced stores ==================
__global__ void k_unperm(const unsigned* __restrict__ inv, const float* __restrict__ r_perm,
                         float* __restrict__ out, int N) {
    const int stride = gridDim.x * blockDim.x;
    for (int t = blockIdx.x * blockDim.x + threadIdx.x; t < N; t += stride)
        out[t] = r_perm[inv[t]];
}

// ===================== fallback (direct) path ===============================
__global__ void k_mask(const int* __restrict__ bat_items, unsigned char* __restrict__ mask,
                       int N) {
    int t = blockIdx.x * blockDim.x + threadIdx.x;
    if (t < N) mask[bat_items[t]] = 1;
}

__global__ void k_ratings(const float* __restrict__ hidden, const float* __restrict__ de_emb,
                          const float* __restrict__ de_bias,
                          const int* __restrict__ bat_idx, const int* __restrict__ bat_items,
                          float* __restrict__ out, int N) {
    const int l = threadIdx.x & 15;
    const int gid = (blockIdx.x * blockDim.x + threadIdx.x) >> 4;
    const int gstride = (gridDim.x * blockDim.x) >> 4;
    for (int n = gid; n < N; n += gstride) {
        int b  = bat_idx[n];
        int it = bat_items[n];
        float4 hv = *reinterpret_cast<const float4*>(hidden + (size_t)b  * 64 + l * 4);
        float4 dv = *reinterpret_cast<const float4*>(de_emb + (size_t)it * 64 + l * 4);
        float s = hv.x*dv.x + hv.y*dv.y + hv.z*dv.z + hv.w*dv.w;
        s += __shfl_xor(s, 1);
        s += __shfl_xor(s, 2);
        s += __shfl_xor(s, 4);
        s += __shfl_xor(s, 8);
        if (l == 0) out[n] = s + de_bias[it];
    }
}

// ===================== hidden construction (fat grid-stride) ================
__global__ void k_scatter(const int* __restrict__ sp_row, const int* __restrict__ sp_col,
                          const float* __restrict__ en_emb, float* __restrict__ hidden,
                          int nnz) {
    const int lane = threadIdx.x & 63;
    const int wave = (blockIdx.x * blockDim.x + threadIdx.x) >> 6;
    const int nwaves = (gridDim.x * blockDim.x) >> 6;
    for (int i = wave; i < nnz; i += nwaves) {
        if (!keep_mask(i, nnz)) continue;       // wave-uniform
        int row = sp_row[i];
        int col = sp_col[i];
        float v = 1.25f * en_emb[(size_t)col * 64 + lane];
        atomicAdd(&hidden[row * 64 + lane], v);
    }
}

__global__ void k_hfinish(float* __restrict__ hidden, const float* __restrict__ user_emb,
                          const int* __restrict__ user_ids, const float* __restrict__ en_off,
                          int B) {
    int t = blockIdx.x * blockDim.x + threadIdx.x;
    if (t >= B * 64) return;
    int b = t >> 6, d = t & 63;
    int uid = user_ids[b];
    float h = hidden[t] + user_emb[(size_t)uid * 64 + d] + en_off[d];
    hidden[t] = tanhf(h);
}

// ===================== fused regularization =================================
__global__ void k_reg(const unsigned char* __restrict__ mask,
                      const float* __restrict__ en_emb, const float* __restrict__ de_emb,
                      const float* __restrict__ de_bias,
                      const float* __restrict__ user_emb, const int* __restrict__ user_ids,
                      const float* __restrict__ en_off,
                      float* __restrict__ reg, int num_items, int B) {
    const int stride = gridDim.x * blockDim.x;
    float s = 0.f;
    for (int t = blockIdx.x * blockDim.x + threadIdx.x; t < num_items * 16; t += stride) {
        int i = t >> 4, l = t & 15;
        if (mask[i]) {
            float4 e = *reinterpret_cast<const float4*>(en_emb + (size_t)i * 64 + l * 4);
            float4 d = *reinterpret_cast<const float4*>(de_emb + (size_t)i * 64 + l * 4);
            s += e.x*e.x + e.y*e.y + e.z*e.z + e.w*e.w
               + d.x*d.x + d.y*d.y + d.z*d.z + d.w*d.w;
            if (l == 0) { float bb = de_bias[i]; s += bb * bb; }
        }
    }
    for (int t = blockIdx.x * blockDim.x + threadIdx.x; t < B * 16; t += stride) {
        int b = t >> 4, l = t & 15;
        int uid = user_ids[b];
        float4 u = *reinterpret_cast<const float4*>(user_emb + (size_t)uid * 64 + l * 4);
        s += u.x*u.x + u.y*u.y + u.z*u.z + u.w*u.w;
    }
    if (blockIdx.x == 0 && threadIdx.x < 64) {
        float o = en_off[threadIdx.x];
        s += o * o;
    }
    for (int m = 1; m < 64; m <<= 1) s += __shfl_xor(s, m);
    __shared__ float wsum[4];
    if ((threadIdx.x & 63) == 0) wsum[threadIdx.x >> 6] = s;
    __syncthreads();
    if (threadIdx.x == 0)
        atomicAdd(reg, 0.5f * (wsum[0] + wsum[1] + wsum[2] + wsum[3]));
}

extern "C" void kernel_launch(void* const* d_in, const int* in_sizes, int n_in,
                              void* d_out, int out_size, void* d_ws, size_t ws_size,
                              hipStream_t stream) {
    const int*   user_ids  = (const int*)  d_in[0];
    const int*   bat_idx   = (const int*)  d_in[1];
    const int*   sp_row    = (const int*)  d_in[2];
    const int*   sp_col    = (const int*)  d_in[3];
    const int*   bat_items = (const int*)  d_in[4];
    const float* en_emb    = (const float*)d_in[5];
    const float* en_off    = (const float*)d_in[6];
    const float* de_emb    = (const float*)d_in[7];
    const float* de_bias   = (const float*)d_in[8];
    const float* user_emb  = (const float*)d_in[9];

    const int B         = in_sizes[0];
    const int N         = in_sizes[1];
    const int NNZ       = in_sizes[2];
    const int NUM_ITEMS = in_sizes[8];

    float* out = (float*)d_out;        // ratings [N]
    float* reg = out + N;              // reg_loss scalar

    // workspace layout: [hidden | mask | cursor] zeroed with ONE memset, then
    // perm / inv / r_perm (no init needed).
    char* ws = (char*)d_ws;
    size_t off = 0;
    float* hidden = (float*)(ws + off);           off += (size_t)B * 64 * sizeof(float);
    unsigned char* mask = (unsigned char*)(ws + off);
    off += ((size_t)NUM_ITEMS + 255) & ~(size_t)255;
    int* cursor = (int*)(ws + off);               off += 256;
    const size_t zero_bytes = off;
    unsigned* perm   = (unsigned*)(ws + off);     off += (size_t)NB * CAPB * 4;
    unsigned* inv    = (unsigned*)(ws + off);     off += (size_t)N * 4;
    float*    r_perm = (float*)(ws + off);        off += (size_t)NB * CAPB * 4;

    const bool sorted_path =
        (ws_size >= off) && (N == (1 << 20)) && (B <= 4096) &&
        (NUM_ITEMS <= (1 << 17)) && (NUM_ITEMS >= 65536);

    hipMemsetAsync(ws, 0, zero_bytes, stream);
    hipMemsetAsync(reg, 0, sizeof(float), stream);

    if (sorted_path) {
        k_bucket<<<256, 256, 0, stream>>>(bat_idx, bat_items, mask, cursor, perm, inv,
                                          N, NUM_ITEMS);
    } else {
        k_mask<<<(N + 255) / 256, 256, 0, stream>>>(bat_items, mask, N);
    }

    k_scatter<<<FATB, 256, 0, stream>>>(sp_row, sp_col, en_emb, hidden, NNZ);
    k_hfinish<<<(B * 64 + 255) / 256, 256, 0, stream>>>(hidden, user_emb, user_ids, en_off, B);

    if (sorted_path) {
        k_ratings_bkt<<<FATB, 256, 0, stream>>>(hidden, de_emb, de_bias, perm, cursor, r_perm);
        k_unperm<<<1024, 256, 0, stream>>>(inv, r_perm, out, N);
    } else {
        k_ratings<<<FATB, 256, 0, stream>>>(hidden, de_emb, de_bias, bat_idx, bat_items, out, N);
    }

    k_reg<<<256, 256, 0, stream>>>(mask, en_emb, de_emb, de_bias,
                                   user_emb, user_ids, en_off, reg, NUM_ITEMS, B);
}

// Round 6
// 236.543 us; speedup vs baseline: 1.4355x; 1.0359x over previous
//
#include <hip/hip_runtime.h>
#include <hip/hip_bf16.h>

// ---------------------------------------------------------------------------
// CDAE forward. Round 6: kill the scatter atomics.
// R5 post-mortem: k_scatter 49.4us, WRITE_SIZE=41MB == 163840 kept-nnz x 256B
// -> every 4B atomicAdd is a device-scope RMW at the memory side (per-XCD L2s
// non-coherent, so agent-scope atomics bypass L2). Bound by memory-side atomic
// rate (4.7ns/wave-atomic), not HBM(17%)/VALU(60%).
// Fix: counting-sort nnz by row (4096 buckets, keep-bit precomputed into the
// payload), then ONE WAVE PER ROW accumulates en_emb rows in registers
// (shfl-broadcast entries, 2 parity accumulators) and writes
// hidden=tanh(1.25*acc+user+off) once -- fuses k_hfinish, removes hidden
// memset, zero global atomics on the fp path. srow aliases r_perm (disjoint
// lifetimes) so ws footprint is unchanged.
// ---------------------------------------------------------------------------
#define PARTITIONABLE 1
#define NB 8               // item-slice buckets == XCDs (blockIdx&7 pinning)
#define CAPB 136192        // per-item-bucket capacity; E=131072, +14 sigma
#define FATB 2048          // fat grid size for ratings
#define CAPR 128           // per-row capacity; E=50, P(Poisson(50)>127)~1e-19
#define RSB 200            // rowsort blocks: NNZ=204800 = 200 * 4 * 256

__device__ __forceinline__ unsigned rotl32(unsigned x, int r) {
    return (x << r) | (x >> (32 - r));
}

__device__ __forceinline__ void threefry2x32(unsigned k0, unsigned k1,
                                             unsigned& x0, unsigned& x1) {
    unsigned ks0 = k0, ks1 = k1, ks2 = k0 ^ k1 ^ 0x1BD11BDAu;
    x0 += ks0; x1 += ks1;
#define TF_R(r) { x0 += x1; x1 = rotl32(x1, r); x1 ^= x0; }
    TF_R(13) TF_R(15) TF_R(26) TF_R(6)   x0 += ks1; x1 += ks2 + 1u;
    TF_R(17) TF_R(29) TF_R(16) TF_R(24)  x0 += ks2; x1 += ks0 + 2u;
    TF_R(13) TF_R(15) TF_R(26) TF_R(6)   x0 += ks0; x1 += ks1 + 3u;
    TF_R(17) TF_R(29) TF_R(16) TF_R(24)  x0 += ks1; x1 += ks2 + 4u;
    TF_R(13) TF_R(15) TF_R(26) TF_R(6)   x0 += ks2; x1 += ks0 + 5u;
#undef TF_R
}

__device__ __forceinline__ bool keep_mask(int i, int nnz) {
#if PARTITIONABLE
    unsigned x0 = 0u, x1 = (unsigned)i;
    threefry2x32(0u, 42u, x0, x1);
    unsigned bits = x0 ^ x1;
#else
    int half = nnz >> 1;
    int j = (i < half) ? i : i - half;
    unsigned x0 = (unsigned)j, x1 = (unsigned)(j + half);
    threefry2x32(0u, 42u, x0, x1);
    unsigned bits = (i < half) ? x0 : x1;
#endif
    float u = __uint_as_float((bits >> 9) | 0x3f800000u) - 1.0f;
    return u < 0.8f;
}

// ===================== pair bucketing by item slice =========================
__global__ void k_bucket(const int* __restrict__ bat_idx, const int* __restrict__ bat_items,
                         unsigned char* __restrict__ mask, int* __restrict__ cursor,
                         unsigned* __restrict__ perm, unsigned* __restrict__ inv,
                         int N, int num_items) {
    __shared__ int h[NB];
    if (threadIdx.x < NB) h[threadIdx.x] = 0;
    __syncthreads();
    const int per = N / gridDim.x;                 // 4096
    const int base_n = blockIdx.x * per;
    const int iters = per / blockDim.x;            // 16
    unsigned packed[16];
    int bkt[16];
    for (int it = 0; it < iters; ++it) {
        int n = base_n + it * blockDim.x + threadIdx.x;
        int item = bat_items[n];
        int bidx = bat_idx[n];
        mask[item] = 1;
        int b = (int)(((unsigned long long)(unsigned)item * NB) / (unsigned)num_items);
        packed[it] = ((unsigned)item << 12) | (unsigned)bidx;   // item:17 | bidx:12
        bkt[it] = b;
        atomicAdd(&h[b], 1);
    }
    __syncthreads();
    if (threadIdx.x < NB) {
        int cnt = h[threadIdx.x];
        h[threadIdx.x] = atomicAdd(&cursor[threadIdx.x], cnt);
    }
    __syncthreads();
    for (int it = 0; it < iters; ++it) {
        int n = base_n + it * blockDim.x + threadIdx.x;
        int b = bkt[it];
        int pos = atomicAdd(&h[b], 1);
        unsigned gpos = (unsigned)b * CAPB + (unsigned)min(pos, CAPB - 1);
        perm[gpos] = packed[it];
        inv[n] = gpos;
    }
}

// ===================== nnz counting-sort by row =============================
// RSB blocks x 256 threads, 4 iters each. Payload: col<<1 | keep.
__global__ void k_rowsort(const int* __restrict__ sp_row, const int* __restrict__ sp_col,
                          int* __restrict__ rowcur, unsigned* __restrict__ srow,
                          int nnz, int B) {
    __shared__ int h[4096];
    for (int i = threadIdx.x; i < B; i += blockDim.x) h[i] = 0;
    __syncthreads();
    const int per = nnz / gridDim.x;               // 1024
    const int base = blockIdx.x * per;
    const int iters = per / blockDim.x;            // 4
    unsigned pk[8];
    int rw[8];
    for (int it = 0; it < iters; ++it) {
        int i = base + it * blockDim.x + threadIdx.x;
        int row = sp_row[i];
        int col = sp_col[i];
        unsigned k = keep_mask(i, nnz) ? 1u : 0u;
        pk[it] = ((unsigned)col << 1) | k;
        rw[it] = row;
        atomicAdd(&h[row], 1);
    }
    __syncthreads();
    for (int i = threadIdx.x; i < B; i += blockDim.x) {
        int cnt = h[i];
        if (cnt) h[i] = atomicAdd(&rowcur[i], cnt);
    }
    __syncthreads();
    for (int it = 0; it < iters; ++it) {
        int row = rw[it];
        int pos = atomicAdd(&h[row], 1);
        srow[(size_t)row * CAPR + min(pos, CAPR - 1)] = pk[it];
    }
}

// ===================== hidden: one wave per row, register accumulate ========
// Fuses segment-sum + user_emb + offset + tanh. No atomics, single store.
__global__ void k_hidden(const unsigned* __restrict__ srow, const int* __restrict__ rowcur,
                         const float* __restrict__ en_emb, const float* __restrict__ user_emb,
                         const int* __restrict__ user_ids, const float* __restrict__ en_off,
                         float* __restrict__ hidden, int B) {
    const int lane = threadIdx.x & 63;
    const int row = (blockIdx.x * blockDim.x + threadIdx.x) >> 6;
    if (row >= B) return;
    const int cnt = min(rowcur[row], CAPR);
    const unsigned* sr = srow + (size_t)row * CAPR;
    float acc0 = 0.f, acc1 = 0.f;
    for (int j0 = 0; j0 < cnt; j0 += 64) {
        unsigned ev = (j0 + lane < cnt) ? sr[j0 + lane] : 0u;
        int m = min(64, cnt - j0);
        int jj = 0;
        for (; jj + 1 < m; jj += 2) {               // 2 independent gather chains
            unsigned e0 = __shfl(ev, jj);
            unsigned e1 = __shfl(ev, jj + 1);
            if (e0 & 1u) acc0 += en_emb[(size_t)(e0 >> 1) * 64 + lane];
            if (e1 & 1u) acc1 += en_emb[(size_t)(e1 >> 1) * 64 + lane];
        }
        if (jj < m) {
            unsigned e0 = __shfl(ev, jj);
            if (e0 & 1u) acc0 += en_emb[(size_t)(e0 >> 1) * 64 + lane];
        }
    }
    int uid = user_ids[row];
    float hval = 1.25f * (acc0 + acc1) + user_emb[(size_t)uid * 64 + lane] + en_off[lane];
    hidden[(size_t)row * 64 + lane] = tanhf(hval);
}

// ===================== ratings: fat grid-stride over XCD-pinned buckets =====
__global__ void k_ratings_bkt(const float* __restrict__ hidden, const float* __restrict__ de_emb,
                              const float* __restrict__ de_bias,
                              const unsigned* __restrict__ perm, const int* __restrict__ cursor,
                              float* __restrict__ r_perm) {
    const int bkt = blockIdx.x & (NB - 1);
    const int cnt = cursor[bkt];
    const int l = threadIdx.x & 15;
    const int gid = (blockIdx.x >> 3) * (blockDim.x >> 4) + (threadIdx.x >> 4);
    const int gpb = (gridDim.x >> 3) * (blockDim.x >> 4);
    const unsigned* pb = perm + (size_t)bkt * CAPB;
    float* rb = r_perm + (size_t)bkt * CAPB;

    int slot = gid;
    for (; slot + gpb < cnt; slot += 2 * gpb) {
        unsigned p0 = pb[slot];
        unsigned p1 = pb[slot + gpb];
        int it0 = (int)(p0 >> 12), b0 = (int)(p0 & 0xFFFu);
        int it1 = (int)(p1 >> 12), b1 = (int)(p1 & 0xFFFu);
        float4 h0 = *reinterpret_cast<const float4*>(hidden + (size_t)b0 * 64 + l * 4);
        float4 d0 = *reinterpret_cast<const float4*>(de_emb + (size_t)it0 * 64 + l * 4);
        float4 h1 = *reinterpret_cast<const float4*>(hidden + (size_t)b1 * 64 + l * 4);
        float4 d1 = *reinterpret_cast<const float4*>(de_emb + (size_t)it1 * 64 + l * 4);
        float s0 = h0.x*d0.x + h0.y*d0.y + h0.z*d0.z + h0.w*d0.w;
        float s1 = h1.x*d1.x + h1.y*d1.y + h1.z*d1.z + h1.w*d1.w;
        s0 += __shfl_xor(s0, 1); s1 += __shfl_xor(s1, 1);
        s0 += __shfl_xor(s0, 2); s1 += __shfl_xor(s1, 2);
        s0 += __shfl_xor(s0, 4); s1 += __shfl_xor(s1, 4);
        s0 += __shfl_xor(s0, 8); s1 += __shfl_xor(s1, 8);
        if (l == 0) {
            rb[slot]       = s0 + de_bias[it0];
            rb[slot + gpb] = s1 + de_bias[it1];
        }
    }
    for (; slot < cnt; slot += gpb) {
        unsigned p = pb[slot];
        int item = (int)(p >> 12), bidx = (int)(p & 0xFFFu);
        float4 hv = *reinterpret_cast<const float4*>(hidden + (size_t)bidx * 64 + l * 4);
        float4 dv = *reinterpret_cast<const float4*>(de_emb + (size_t)item * 64 + l * 4);
        float s = hv.x*dv.x + hv.y*dv.y + hv.z*dv.z + hv.w*dv.w;
        s += __shfl_xor(s, 1);
        s += __shfl_xor(s, 2);
        s += __shfl_xor(s, 4);
        s += __shfl_xor(s, 8);
        if (l == 0) rb[slot] = s + de_bias[item];
    }
}

// ===================== unpermute: gather, coalesced stores ==================
__global__ void k_unperm(const unsigned* __restrict__ inv, const float* __restrict__ r_perm,
                         float* __restrict__ out, int N) {
    const int stride = gridDim.x * blockDim.x;
    for (int t = blockIdx.x * blockDim.x + threadIdx.x; t < N; t += stride)
        out[t] = r_perm[inv[t]];
}

// ===================== fallback (direct) path ===============================
__global__ void k_mask(const int* __restrict__ bat_items, unsigned char* __restrict__ mask,
                       int N) {
    int t = blockIdx.x * blockDim.x + threadIdx.x;
    if (t < N) mask[bat_items[t]] = 1;
}

__global__ void k_ratings(const float* __restrict__ hidden, const float* __restrict__ de_emb,
                          const float* __restrict__ de_bias,
                          const int* __restrict__ bat_idx, const int* __restrict__ bat_items,
                          float* __restrict__ out, int N) {
    const int l = threadIdx.x & 15;
    const int gid = (blockIdx.x * blockDim.x + threadIdx.x) >> 4;
    const int gstride = (gridDim.x * blockDim.x) >> 4;
    for (int n = gid; n < N; n += gstride) {
        int b  = bat_idx[n];
        int it = bat_items[n];
        float4 hv = *reinterpret_cast<const float4*>(hidden + (size_t)b  * 64 + l * 4);
        float4 dv = *reinterpret_cast<const float4*>(de_emb + (size_t)it * 64 + l * 4);
        float s = hv.x*dv.x + hv.y*dv.y + hv.z*dv.z + hv.w*dv.w;
        s += __shfl_xor(s, 1);
        s += __shfl_xor(s, 2);
        s += __shfl_xor(s, 4);
        s += __shfl_xor(s, 8);
        if (l == 0) out[n] = s + de_bias[it];
    }
}

__global__ void k_scatter(const int* __restrict__ sp_row, const int* __restrict__ sp_col,
                          const float* __restrict__ en_emb, float* __restrict__ hidden,
                          int nnz) {
    const int lane = threadIdx.x & 63;
    const int wave = (blockIdx.x * blockDim.x + threadIdx.x) >> 6;
    const int nwaves = (gridDim.x * blockDim.x) >> 6;
    for (int i = wave; i < nnz; i += nwaves) {
        if (!keep_mask(i, nnz)) continue;
        int row = sp_row[i];
        int col = sp_col[i];
        float v = 1.25f * en_emb[(size_t)col * 64 + lane];
        atomicAdd(&hidden[row * 64 + lane], v);
    }
}

__global__ void k_hfinish(float* __restrict__ hidden, const float* __restrict__ user_emb,
                          const int* __restrict__ user_ids, const float* __restrict__ en_off,
                          int B) {
    int t = blockIdx.x * blockDim.x + threadIdx.x;
    if (t >= B * 64) return;
    int b = t >> 6, d = t & 63;
    int uid = user_ids[b];
    float h = hidden[t] + user_emb[(size_t)uid * 64 + d] + en_off[d];
    hidden[t] = tanhf(h);
}

// ===================== fused regularization =================================
__global__ void k_reg(const unsigned char* __restrict__ mask,
                      const float* __restrict__ en_emb, const float* __restrict__ de_emb,
                      const float* __restrict__ de_bias,
                      const float* __restrict__ user_emb, const int* __restrict__ user_ids,
                      const float* __restrict__ en_off,
                      float* __restrict__ reg, int num_items, int B) {
    const int stride = gridDim.x * blockDim.x;
    float s = 0.f;
    for (int t = blockIdx.x * blockDim.x + threadIdx.x; t < num_items * 16; t += stride) {
        int i = t >> 4, l = t & 15;
        if (mask[i]) {
            float4 e = *reinterpret_cast<const float4*>(en_emb + (size_t)i * 64 + l * 4);
            float4 d = *reinterpret_cast<const float4*>(de_emb + (size_t)i * 64 + l * 4);
            s += e.x*e.x + e.y*e.y + e.z*e.z + e.w*e.w
               + d.x*d.x + d.y*d.y + d.z*d.z + d.w*d.w;
            if (l == 0) { float bb = de_bias[i]; s += bb * bb; }
        }
    }
    for (int t = blockIdx.x * blockDim.x + threadIdx.x; t < B * 16; t += stride) {
        int b = t >> 4, l = t & 15;
        int uid = user_ids[b];
        float4 u = *reinterpret_cast<const float4*>(user_emb + (size_t)uid * 64 + l * 4);
        s += u.x*u.x + u.y*u.y + u.z*u.z + u.w*u.w;
    }
    if (blockIdx.x == 0 && threadIdx.x < 64) {
        float o = en_off[threadIdx.x];
        s += o * o;
    }
    for (int m = 1; m < 64; m <<= 1) s += __shfl_xor(s, m);
    __shared__ float wsum[4];
    if ((threadIdx.x & 63) == 0) wsum[threadIdx.x >> 6] = s;
    __syncthreads();
    if (threadIdx.x == 0)
        atomicAdd(reg, 0.5f * (wsum[0] + wsum[1] + wsum[2] + wsum[3]));
}

extern "C" void kernel_launch(void* const* d_in, const int* in_sizes, int n_in,
                              void* d_out, int out_size, void* d_ws, size_t ws_size,
                              hipStream_t stream) {
    const int*   user_ids  = (const int*)  d_in[0];
    const int*   bat_idx   = (const int*)  d_in[1];
    const int*   sp_row    = (const int*)  d_in[2];
    const int*   sp_col    = (const int*)  d_in[3];
    const int*   bat_items = (const int*)  d_in[4];
    const float* en_emb    = (const float*)d_in[5];
    const float* en_off    = (const float*)d_in[6];
    const float* de_emb    = (const float*)d_in[7];
    const float* de_bias   = (const float*)d_in[8];
    const float* user_emb  = (const float*)d_in[9];

    const int B         = in_sizes[0];
    const int N         = in_sizes[1];
    const int NNZ       = in_sizes[2];
    const int NUM_ITEMS = in_sizes[8];

    float* out = (float*)d_out;        // ratings [N]
    float* reg = out + N;              // reg_loss scalar

    // workspace: [mask | cursor | rowcur] = single small memset region, then
    // hidden (write-only) | perm | inv | r_perm (srow aliases r_perm).
    char* ws = (char*)d_ws;
    size_t off = 0;
    unsigned char* mask = (unsigned char*)(ws + off);
    off += ((size_t)NUM_ITEMS + 255) & ~(size_t)255;
    int* cursor = (int*)(ws + off);               off += 256;
    int* rowcur = (int*)(ws + off);               off += (size_t)B * sizeof(int);
    const size_t zero_bytes = off;
    float* hidden = (float*)(ws + off);           off += (size_t)B * 64 * sizeof(float);
    unsigned* perm   = (unsigned*)(ws + off);     off += (size_t)NB * CAPB * 4;
    unsigned* inv    = (unsigned*)(ws + off);     off += (size_t)N * 4;
    float*    r_perm = (float*)(ws + off);
    unsigned* srow   = (unsigned*)r_perm;         // alias: disjoint lifetimes
    size_t tail = (size_t)NB * CAPB * 4;
    if ((size_t)B * CAPR * 4 > tail) tail = (size_t)B * CAPR * 4;
    off += tail;

    const bool sorted_path =
        (ws_size >= off) && (N == (1 << 20)) && (B == 4096) &&
        (NUM_ITEMS <= (1 << 17)) && (NUM_ITEMS >= 65536) &&
        (NNZ % (RSB * 256) == 0) && (NNZ / RSB <= CAPR * 256);

    hipMemsetAsync(ws, 0, zero_bytes, stream);
    hipMemsetAsync(reg, 0, sizeof(float), stream);

    if (sorted_path) {
        k_bucket <<<256, 256, 0, stream>>>(bat_idx, bat_items, mask, cursor, perm, inv,
                                           N, NUM_ITEMS);
        k_rowsort<<<RSB, 256, 0, stream>>>(sp_row, sp_col, rowcur, srow, NNZ, B);
        k_hidden <<<(B * 64 + 255) / 256, 256, 0, stream>>>(
            srow, rowcur, en_emb, user_emb, user_ids, en_off, hidden, B);
        k_ratings_bkt<<<FATB, 256, 0, stream>>>(hidden, de_emb, de_bias, perm, cursor, r_perm);
        k_unperm<<<1024, 256, 0, stream>>>(inv, r_perm, out, N);
    } else {
        hipMemsetAsync(hidden, 0, (size_t)B * 64 * sizeof(float), stream);
        k_mask<<<(N + 255) / 256, 256, 0, stream>>>(bat_items, mask, N);
        k_scatter<<<FATB, 256, 0, stream>>>(sp_row, sp_col, en_emb, hidden, NNZ);
        k_hfinish<<<(B * 64 + 255) / 256, 256, 0, stream>>>(hidden, user_emb, user_ids,
                                                            en_off, B);
        k_ratings<<<FATB, 256, 0, stream>>>(hidden, de_emb, de_bias, bat_idx, bat_items, out, N);
    }

    k_reg<<<256, 256, 0, stream>>>(mask, en_emb, de_emb, de_bias,
                                   user_emb, user_ids, en_off, reg, NUM_ITEMS, B);
}